// Round 11
// baseline (165.842 us; speedup 1.0000x reference)
//
#include <hip/hip_runtime.h>
#include <hip/hip_bf16.h>

// PointConv: N=32768 points, E=786432 edges (sorted by out_index), K<=64
// product[n][c][m] = inv_n * sum_edges x_in[src][c] * celu(celu(pos_local@W1)@W2)[m]
// out[n][k] = product[n].flat(1024) @ W3[1024][64] + b3[k]
//
// R11: R10 + cross-iteration x prefetch: next batch's ax gathered during the
// current batch's h2-MFMA section; P-MFMA consumes last iteration's ax.

typedef __attribute__((ext_vector_type(8))) short short8;
typedef __attribute__((ext_vector_type(4))) float f32x4;
typedef __attribute__((ext_vector_type(2))) unsigned int u32x2;
typedef __attribute__((ext_vector_type(4))) unsigned int u32x4;
typedef __fp16 f16x2 __attribute__((ext_vector_type(2)));
typedef __fp16 f16x8 __attribute__((ext_vector_type(8)));

static __device__ __forceinline__ int rfl(int v){
    return __builtin_amdgcn_readfirstlane(v);
}
static __device__ __forceinline__ float celu1(float x){
    return x > 0.0f ? x : (__expf(x) - 1.0f);
}
static __device__ __forceinline__ unsigned int pkh(float lo, float hi){
    f16x2 t = __builtin_amdgcn_cvt_pkrtz(lo, hi);
    return __builtin_bit_cast(unsigned int, t);
}

// ---------------- Kernel 0: seg boundaries + W3/W2 prep (merged) -------------
__global__ void setup_kernel(const int* __restrict__ out_index,
                             int* __restrict__ seg_start, int E, int N,
                             const float* __restrict__ W3, const float* __restrict__ W2,
                             __fp16* __restrict__ W3frag,
                             unsigned int* __restrict__ W2f16)
{
    int o = blockIdx.x * blockDim.x + threadIdx.x;
    if (o < E) {
        int cur = out_index[o];
        if (o == 0) {
            for (int v = 0; v <= cur; ++v) seg_start[v] = 0;
        } else {
            int prev = out_index[o - 1];
            for (int v = prev + 1; v <= cur; ++v) seg_start[v] = o;
        }
        if (o == E - 1) {
            for (int v = cur + 1; v <= N; ++v) seg_start[v] = E;
        }
    }
    if (o < 65536) {
        int j    = o & 7;
        int lane = (o >> 3) & 63;
        int t    = (o >> 9) & 3;
        int kk   = o >> 11;
        int k = kk * 32 + (lane >> 4) * 8 + j;
        int n = t * 16 + (lane & 15);
        W3frag[o] = (__fp16)W3[k * 64 + n];
    } else if (o < 65536 + 1024) {
        int o2 = o - 65536;
        int nt   = o2 >> 8;
        int lane = (o2 >> 2) & 63;
        int d    = o2 & 3;
        int q = lane >> 4, rr = lane & 15;
        unsigned int v = 0;
        if (q < 2) {
            int k0 = q * 8 + 2 * d;
            int n = nt * 16 + rr;
            v = pkh(W2[k0 * 64 + n], W2[(k0 + 1) * 64 + n]);
        }
        W2f16[o2] = v;
    }
}

// ---------------- Kernel 1: edge aggregation (pipelined all-MFMA) ------------
// Wave w owns points [4w, 4w+4). Batch = 64 slots (2x 32-slot K-steps).
// Pipeline: prefetch next batch's descriptors, in_index vector, pos rows AND
// x A-frags while computing the current batch.
__global__ __launch_bounds__(256) void agg_kernel(
    const float* __restrict__ x_in, const float* __restrict__ pos_in,
    const float* __restrict__ pos_out, const int* __restrict__ in_index,
    const int* __restrict__ seg_start, const float* __restrict__ W1,
    const unsigned int* __restrict__ W2f16, __fp16* __restrict__ Pf16, int E)
{
    __shared__ __align__(16) unsigned char ldsraw[4 * 9216];
    int lane = threadIdx.x & 63;
    int wv = threadIdx.x >> 6;
    unsigned char* H2L = ldsraw + wv * 9216;   // staging 0..3071; tile rows m*144
    int w = blockIdx.x * 4 + wv;

    int r = lane & 15;
    int q = lane >> 4;
    int l31 = lane & 31;
    bool hihalf = lane >= 32;
    int vq = 32 * q;                           // byte-addr component for bpermute

    // zero block for padded-K A-frag lanes (bytes 9200..9215 never written)
    if (lane == 0) *(u32x4*)(H2L + 9200) = (u32x4){0u, 0u, 0u, 0u};

    // W2 B-frags (constant)
    f16x8 bfr[4];
    #pragma unroll
    for (int nt = 0; nt < 4; ++nt)
        bfr[nt] = __builtin_bit_cast(f16x8, *((const u32x4*)W2f16 + nt * 64 + lane));

    // W1 columns (uniform -> SGPRs)
    float w1a[16], w1b[16], w1c[16];
    #pragma unroll
    for (int c = 0; c < 16; ++c) { w1a[c] = W1[c]; w1b[c] = W1[16 + c]; w1c[c] = W1[32 + c]; }

    // per-wave point table (4 points, wave-uniform)
    int s5[5];
    #pragma unroll
    for (int i = 0; i < 5; ++i) s5[i] = rfl(seg_start[w * 4 + i]);
    int cf[4], cc[4], p[5];
    p[0] = 0;
    #pragma unroll
    for (int i = 0; i < 4; ++i) {
        cf[i] = s5[i + 1] - s5[i];
        cc[i] = cf[i] > 64 ? 64 : cf[i];
        p[i + 1] = p[i] + (cc[i] > 32 ? 2 : 1);
    }
    int ns = p[4];                             // total 32-slot steps, 4..8

    // descriptor for step t (wave-uniform; t >= ns yields rem<=0 -> all-pad)
    #define STEP_DESC(t, nS, cfS, remS, ebS)                         \
        {                                                            \
            int i_ = 0, pi_ = 0;                                     \
            _Pragma("unroll")                                        \
            for (int k_ = 1; k_ < 4; ++k_)                           \
                if ((t) >= p[k_]) { i_ = k_; pi_ = p[k_]; }          \
            int cf_ = cf[0], cc_ = cc[0], sg_ = s5[0];               \
            _Pragma("unroll")                                        \
            for (int k_ = 1; k_ < 4; ++k_)                           \
                if (i_ >= k_) { cf_ = cf[k_]; cc_ = cc[k_]; sg_ = s5[k_]; } \
            int kb_ = ((t) - pi_) * 32;                              \
            (nS) = w * 4 + i_; (cfS) = cf_;                          \
            (remS) = cc_ - kb_; (ebS) = sg_ + kb_;                   \
        }

    // masked x A-frag gather for one 32-slot half (slot index = 32h+8q+jj)
    #define GATHER_AX(dst, idxv, remS, h)                            \
        {                                                            \
            float xv_[8];                                            \
            _Pragma("unroll")                                        \
            for (int jj_ = 0; jj_ < 8; ++jj_) {                      \
                int s_ = __builtin_amdgcn_ds_bpermute(                \
                    128 * (h) + vq + 4 * jj_, (idxv));               \
                float x_ = x_in[s_ * 16 + r];                        \
                xv_[jj_] = ((8 * q + jj_) < (remS)) ? x_ : 0.0f;     \
            }                                                        \
            u32x4 t_;                                                \
            _Pragma("unroll")                                        \
            for (int d_ = 0; d_ < 4; ++d_)                           \
                t_[d_] = pkh(xv_[2 * d_], xv_[2 * d_ + 1]);          \
            (dst) = __builtin_bit_cast(f16x8, t_);                   \
        }

    f32x4 C[4];
    #pragma unroll
    for (int mt = 0; mt < 4; ++mt) C[mt] = (f32x4){0.f, 0.f, 0.f, 0.f};
    int cur_n = w * 4;
    int cur_cf = cf[0];

    // ---- prologue: batch 0 descriptors + idx + pos + x prefetch ----
    int nA, cfA, remA, ebA, nB, cfB, remB, ebB;
    STEP_DESC(0, nA, cfA, remA, ebA)
    STEP_DESC(1, nB, cfB, remB, ebB)
    int nH = hihalf ? nB : nA;
    int ebH = hihalf ? ebB : ebA;
    int idx0 = ebH + l31; idx0 = idx0 < E ? idx0 : E - 1;
    int idxs = in_index[idx0];                 // lane l -> src of slot l
    float pox = pos_out[nH * 3 + 0];
    float poy = pos_out[nH * 3 + 1];
    float poz = pos_out[nH * 3 + 2];
    float pi0 = pos_in[idxs * 3 + 0];
    float pi1 = pos_in[idxs * 3 + 1];
    float pi2 = pos_in[idxs * 3 + 2];
    f16x8 ax[2];
    GATHER_AX(ax[0], idxs, remA, 0)
    GATHER_AX(ax[1], idxs, remB, 1)

    #pragma unroll 1
    for (int b = 0; b < 4; ++b) {
        if (2 * b >= ns) break;

        // ---- prefetch next batch: descriptors + idx vector ----
        int nA2, cfA2, remA2, ebA2, nB2, cfB2, remB2, ebB2;
        STEP_DESC(2 * b + 2, nA2, cfA2, remA2, ebA2)
        STEP_DESC(2 * b + 3, nB2, cfB2, remB2, ebB2)
        int nH2 = hihalf ? nB2 : nA2;
        int ebH2 = hihalf ? ebB2 : ebA2;
        int idx2 = ebH2 + l31; idx2 = idx2 < E ? idx2 : E - 1;
        int idxs_next = in_index[idx2];
        float pox2 = pos_out[nH2 * 3 + 0];
        float poy2 = pos_out[nH2 * 3 + 1];
        float poz2 = pos_out[nH2 * 3 + 2];

        // ---- h1 (lane = slot): pos already prefetched ----
        float d0 = pi0 - pox;
        float d1 = pi1 - poy;
        float d2 = pi2 - poz;
        unsigned int hp[8];
        #pragma unroll
        for (int cp = 0; cp < 8; ++cp) {
            float a0 = celu1(fmaf(d0, w1a[2 * cp],     fmaf(d1, w1b[2 * cp],     d2 * w1c[2 * cp])));
            float a1 = celu1(fmaf(d0, w1a[2 * cp + 1], fmaf(d1, w1b[2 * cp + 1], d2 * w1c[2 * cp + 1])));
            hp[cp] = pkh(a0, a1);
        }
        *(u32x4*)(H2L + lane * 48)      = (u32x4){hp[0], hp[1], hp[2], hp[3]};
        *(u32x4*)(H2L + lane * 48 + 16) = (u32x4){hp[4], hp[5], hp[6], hp[7]};
        f16x8 af[4];
        #pragma unroll
        for (int et = 0; et < 4; ++et) {
            int abase = (q < 2) ? ((et * 16 + r) * 48 + q * 16) : 9200;
            af[et] = __builtin_bit_cast(f16x8, *(const u32x4*)(H2L + abase));
        }

        // ---- x prefetch for NEXT batch (covered by the h2 section below) ----
        f16x8 ax_next[2];
        GATHER_AX(ax_next[0], idxs_next, remA2, 0)
        GATHER_AX(ax_next[1], idxs_next, remB2, 1)
        // pos prefetch for next batch
        float pi0n = pos_in[idxs_next * 3 + 0];
        float pi1n = pos_in[idxs_next * 3 + 1];
        float pi2n = pos_in[idxs_next * 3 + 2];

        // ---- h2 = celu(h1 @ W2) via MFMA; tile write H2L[m][slot] ----
        #pragma unroll
        for (int pp = 0; pp < 2; ++pp) {
            f32x4 D[4][2];
            #pragma unroll
            for (int et = 0; et < 4; ++et)
                #pragma unroll
                for (int j = 0; j < 2; ++j)
                    D[et][j] = __builtin_amdgcn_mfma_f32_16x16x32_f16(
                        af[et], bfr[2 * pp + j], (f32x4){0.f, 0.f, 0.f, 0.f}, 0, 0, 0);
            #pragma unroll
            for (int et = 0; et < 4; ++et)
                #pragma unroll
                for (int j = 0; j < 2; ++j) {
                    int nt = 2 * pp + j;
                    float v0 = celu1(D[et][j][0]);
                    float v1 = celu1(D[et][j][1]);
                    float v2 = celu1(D[et][j][2]);
                    float v3 = celu1(D[et][j][3]);
                    *(u32x2*)(H2L + (nt * 16 + r) * 144 + et * 32 + q * 8) =
                        (u32x2){pkh(v0, v1), pkh(v2, v3)};
                }
        }

        // ---- P accumulation per half, flush on wave-uniform transitions ----
        #pragma unroll
        for (int h = 0; h < 2; ++h) {
            int nS  = h ? nB : nA;
            int cfS = h ? cfB : cfA;
            if (rfl(nS) != cur_n) {
                float inv = cur_cf > 0 ? 1.0f / (float)cur_cf : 0.0f;
                #pragma unroll
                for (int mt = 0; mt < 4; ++mt)
                    #pragma unroll
                    for (int i = 0; i < 4; ++i)
                        Pf16[(size_t)cur_n * 1024 + (q * 4 + i) * 64 + mt * 16 + r] =
                            (__fp16)(C[mt][i] * inv);
                #pragma unroll
                for (int mt = 0; mt < 4; ++mt) C[mt] = (f32x4){0.f, 0.f, 0.f, 0.f};
                cur_n = nS; cur_cf = cfS;
            }
            #pragma unroll
            for (int mt = 0; mt < 4; ++mt) {
                f16x8 bb = __builtin_bit_cast(f16x8,
                    *(u32x4*)(H2L + (mt * 16 + r) * 144 + h * 64 + q * 16));
                C[mt] = __builtin_amdgcn_mfma_f32_16x16x32_f16(ax[h], bb, C[mt], 0, 0, 0);
            }
        }

        // ---- rotate pipeline registers ----
        nA = nA2; cfA = cfA2; remA = remA2; ebA = ebA2;
        nB = nB2; cfB = cfB2; remB = remB2; ebB = ebB2;
        idxs = idxs_next;
        pox = pox2; poy = poy2; poz = poz2;
        pi0 = pi0n; pi1 = pi1n; pi2 = pi2n;
        ax[0] = ax_next[0]; ax[1] = ax_next[1];
    }

    // final flush
    {
        float inv = cur_cf > 0 ? 1.0f / (float)cur_cf : 0.0f;
        #pragma unroll
        for (int mt = 0; mt < 4; ++mt)
            #pragma unroll
            for (int i = 0; i < 4; ++i)
                Pf16[(size_t)cur_n * 1024 + (q * 4 + i) * 64 + mt * 16 + r] =
                    (__fp16)(C[mt][i] * inv);
    }
    #undef STEP_DESC
    #undef GATHER_AX
}

// ---------------- Kernel 2: out = Pf16 @ W3 + b3 (f16 MFMA) ------------------
__global__ __launch_bounds__(256) void gemm_kernel(
    const __fp16* __restrict__ Pf16,
    const __fp16* __restrict__ W3frag,
    const float* __restrict__ b3, float* __restrict__ out)
{
    int lane = threadIdx.x & 63;
    int w = blockIdx.x * 4 + (threadIdx.x >> 6);
    int ptile = w >> 2;
    int ntile = w & 3;
    int quad = lane >> 4;
    int r = lane & 15;

    const short8* Arow = (const short8*)(Pf16 + (size_t)(ptile * 16 + r) * 1024 + quad * 8);
    const short8* Bp   = (const short8*)W3frag + (size_t)ntile * 64 + lane;

    f32x4 acc = {0.0f, 0.0f, 0.0f, 0.0f};
    #pragma unroll 8
    for (int kk = 0; kk < 32; ++kk) {
        f16x8 a = __builtin_bit_cast(f16x8, Arow[kk * 4]);
        f16x8 b = __builtin_bit_cast(f16x8, Bp[(size_t)kk * 256]);
        acc = __builtin_amdgcn_mfma_f32_16x16x32_f16(a, b, acc, 0, 0, 0);
    }

    int outcol = ntile * 16 + r;
    float bias = b3[outcol];
    #pragma unroll
    for (int i = 0; i < 4; ++i) {
        int prow = ptile * 16 + quad * 4 + i;
        out[(size_t)prow * 64 + outcol] = acc[i] + bias;
    }
}

extern "C" void kernel_launch(void* const* d_in, const int* in_sizes, int n_in,
                              void* d_out, int out_size, void* d_ws, size_t ws_size,
                              hipStream_t stream)
{
    const float* x_in    = (const float*)d_in[0];
    const float* pos_in  = (const float*)d_in[1];
    const float* pos_out = (const float*)d_in[2];
    const int* in_index  = (const int*)d_in[3];
    const int* out_index = (const int*)d_in[4];
    const float* W1 = (const float*)d_in[5];
    const float* W2 = (const float*)d_in[6];
    const float* W3 = (const float*)d_in[7];
    const float* b3 = (const float*)d_in[8];

    int N = in_sizes[0] / 16;    // 32768
    int E = in_sizes[3];         // 786432
    float* out = (float*)d_out;

    // workspace: Pf16 (64MB) | seg (N+1) | W3frag (128KB) | W2f16 (4KB)
    char* ws = (char*)d_ws;
    __fp16* Pf16 = (__fp16*)ws;
    size_t off = (size_t)N * 1024 * 2;
    int* seg = (int*)(ws + off);
    off += (((size_t)(N + 1) * 4 + 255) & ~(size_t)255);
    __fp16* W3frag = (__fp16*)(ws + off);
    off += (size_t)65536 * 2;
    unsigned int* W2f16 = (unsigned int*)(ws + off);

    setup_kernel<<<(E + 255) / 256, 256, 0, stream>>>(out_index, seg, E, N,
                                                      W3, W2, W3frag, W2f16);
    agg_kernel<<<N / 16, 256, 0, stream>>>(x_in, pos_in, pos_out, in_index, seg,
                                           W1, W2f16, Pf16, E);
    gemm_kernel<<<N / 16, 256, 0, stream>>>(Pf16, W3frag, b3, out);
}

// Round 12
// 134.323 us; speedup vs baseline: 1.2347x; 1.2347x over previous
//
#include <hip/hip_runtime.h>
#include <hip/hip_bf16.h>

// PointConv: N=32768 points, E=786432 edges (sorted by out_index), K<=64
// product[n][c][m] = inv_n * sum_edges x_in[src][c] * celu(celu(pos_local@W1)@W2)[m]
// out[n][k] = product[n].flat(1024) @ W3[1024][64] + b3[k]
//
// R12: agg = R10 structure (x gather at loop top; no R11 mid-loop prefetch)
// with 2 points/wave (4096 blocks, tail smoothing); gemm reg-blocked 2 ptiles
// x 4 ntiles per wave (halves W3frag L2 traffic).

typedef __attribute__((ext_vector_type(8))) short short8;
typedef __attribute__((ext_vector_type(4))) float f32x4;
typedef __attribute__((ext_vector_type(2))) unsigned int u32x2;
typedef __attribute__((ext_vector_type(4))) unsigned int u32x4;
typedef __fp16 f16x2 __attribute__((ext_vector_type(2)));
typedef __fp16 f16x8 __attribute__((ext_vector_type(8)));

static __device__ __forceinline__ int rfl(int v){
    return __builtin_amdgcn_readfirstlane(v);
}
static __device__ __forceinline__ float celu1(float x){
    return x > 0.0f ? x : (__expf(x) - 1.0f);
}
static __device__ __forceinline__ unsigned int pkh(float lo, float hi){
    f16x2 t = __builtin_amdgcn_cvt_pkrtz(lo, hi);
    return __builtin_bit_cast(unsigned int, t);
}

// ---------------- Kernel 0: seg boundaries + W3/W2 prep (merged) -------------
__global__ void setup_kernel(const int* __restrict__ out_index,
                             int* __restrict__ seg_start, int E, int N,
                             const float* __restrict__ W3, const float* __restrict__ W2,
                             __fp16* __restrict__ W3frag,
                             unsigned int* __restrict__ W2f16)
{
    int o = blockIdx.x * blockDim.x + threadIdx.x;
    if (o < E) {
        int cur = out_index[o];
        if (o == 0) {
            for (int v = 0; v <= cur; ++v) seg_start[v] = 0;
        } else {
            int prev = out_index[o - 1];
            for (int v = prev + 1; v <= cur; ++v) seg_start[v] = o;
        }
        if (o == E - 1) {
            for (int v = cur + 1; v <= N; ++v) seg_start[v] = E;
        }
    }
    if (o < 65536) {
        int j    = o & 7;
        int lane = (o >> 3) & 63;
        int t    = (o >> 9) & 3;
        int kk   = o >> 11;
        int k = kk * 32 + (lane >> 4) * 8 + j;
        int n = t * 16 + (lane & 15);
        W3frag[o] = (__fp16)W3[k * 64 + n];
    } else if (o < 65536 + 1024) {
        int o2 = o - 65536;
        int nt   = o2 >> 8;
        int lane = (o2 >> 2) & 63;
        int d    = o2 & 3;
        int q = lane >> 4, rr = lane & 15;
        unsigned int v = 0;
        if (q < 2) {
            int k0 = q * 8 + 2 * d;
            int n = nt * 16 + rr;
            v = pkh(W2[k0 * 64 + n], W2[(k0 + 1) * 64 + n]);
        }
        W2f16[o2] = v;
    }
}

// ---------------- Kernel 1: edge aggregation (pipelined all-MFMA) ------------
// Wave w owns points [2w, 2w+2). Batch = 64 slots (2x 32-slot K-steps).
// Pipeline: prefetch next batch's descriptors + in_index vector + pos rows
// while computing current batch; x gathered at loop top from current idxs.
__global__ __launch_bounds__(256) void agg_kernel(
    const float* __restrict__ x_in, const float* __restrict__ pos_in,
    const float* __restrict__ pos_out, const int* __restrict__ in_index,
    const int* __restrict__ seg_start, const float* __restrict__ W1,
    const unsigned int* __restrict__ W2f16, __fp16* __restrict__ Pf16, int E)
{
    __shared__ __align__(16) unsigned char ldsraw[4 * 9216];
    int lane = threadIdx.x & 63;
    int wv = threadIdx.x >> 6;
    unsigned char* H2L = ldsraw + wv * 9216;   // staging 0..3071; tile rows m*144
    int w = blockIdx.x * 4 + wv;

    int r = lane & 15;
    int q = lane >> 4;
    int l31 = lane & 31;
    bool hihalf = lane >= 32;
    int vq = 32 * q;                           // byte-addr component for bpermute

    // zero block for padded-K A-frag lanes (bytes 9200..9215 never written)
    if (lane == 0) *(u32x4*)(H2L + 9200) = (u32x4){0u, 0u, 0u, 0u};

    // W2 B-frags (constant)
    f16x8 bfr[4];
    #pragma unroll
    for (int nt = 0; nt < 4; ++nt)
        bfr[nt] = __builtin_bit_cast(f16x8, *((const u32x4*)W2f16 + nt * 64 + lane));

    // W1 columns (uniform -> SGPRs)
    float w1a[16], w1b[16], w1c[16];
    #pragma unroll
    for (int c = 0; c < 16; ++c) { w1a[c] = W1[c]; w1b[c] = W1[16 + c]; w1c[c] = W1[32 + c]; }

    // per-wave point table (2 points, wave-uniform)
    int s3[3];
    #pragma unroll
    for (int i = 0; i < 3; ++i) s3[i] = rfl(seg_start[w * 2 + i]);
    int cf[2], cc[2], p[3];
    p[0] = 0;
    #pragma unroll
    for (int i = 0; i < 2; ++i) {
        cf[i] = s3[i + 1] - s3[i];
        cc[i] = cf[i] > 64 ? 64 : cf[i];
        p[i + 1] = p[i] + (cc[i] > 32 ? 2 : 1);
    }
    int ns = p[2];                             // total 32-slot steps, 2..4

    // descriptor for step t (wave-uniform; t >= ns yields rem<=0 -> all-pad)
    #define STEP_DESC(t, nS, cfS, remS, ebS)                         \
        {                                                            \
            int i_ = 0, pi_ = 0;                                     \
            if ((t) >= p[1]) { i_ = 1; pi_ = p[1]; }                 \
            int cf_ = cf[0], cc_ = cc[0], sg_ = s3[0];               \
            if (i_ >= 1) { cf_ = cf[1]; cc_ = cc[1]; sg_ = s3[1]; }  \
            int kb_ = ((t) - pi_) * 32;                              \
            (nS) = w * 2 + i_; (cfS) = cf_;                          \
            (remS) = cc_ - kb_; (ebS) = sg_ + kb_;                   \
        }

    f32x4 C[4];
    #pragma unroll
    for (int mt = 0; mt < 4; ++mt) C[mt] = (f32x4){0.f, 0.f, 0.f, 0.f};
    int cur_n = w * 2;
    int cur_cf = cf[0];

    // ---- prologue: batch 0 descriptors + idx + pos prefetch ----
    int nA, cfA, remA, ebA, nB, cfB, remB, ebB;
    STEP_DESC(0, nA, cfA, remA, ebA)
    STEP_DESC(1, nB, cfB, remB, ebB)
    int nH = hihalf ? nB : nA;
    int ebH = hihalf ? ebB : ebA;
    int idx0 = ebH + l31; idx0 = idx0 < E ? idx0 : E - 1;
    int idxs = in_index[idx0];                 // lane l -> src of slot l
    float pox = pos_out[nH * 3 + 0];
    float poy = pos_out[nH * 3 + 1];
    float poz = pos_out[nH * 3 + 2];
    float pi0 = pos_in[idxs * 3 + 0];
    float pi1 = pos_in[idxs * 3 + 1];
    float pi2 = pos_in[idxs * 3 + 2];

    #pragma unroll 1
    for (int b = 0; b < 2; ++b) {
        if (2 * b >= ns) break;

        // ---- prefetch next batch: descriptors + idx vector ----
        int nA2, cfA2, remA2, ebA2, nB2, cfB2, remB2, ebB2;
        STEP_DESC(2 * b + 2, nA2, cfA2, remA2, ebA2)
        STEP_DESC(2 * b + 3, nB2, cfB2, remB2, ebB2)
        int nH2 = hihalf ? nB2 : nA2;
        int ebH2 = hihalf ? ebB2 : ebA2;
        int idx2 = ebH2 + l31; idx2 = idx2 < E ? idx2 : E - 1;
        int idxs_next = in_index[idx2];
        float pox2 = pos_out[nH2 * 3 + 0];
        float poy2 = pos_out[nH2 * 3 + 1];
        float poz2 = pos_out[nH2 * 3 + 2];

        // ---- x A-frags: src via bpermute of idxs (loaded last iter) ----
        f16x8 ax[2];
        #pragma unroll
        for (int h = 0; h < 2; ++h) {
            int remS = h ? remB : remA;
            float xv[8];
            #pragma unroll
            for (int jj = 0; jj < 8; ++jj) {
                // slot = 32h + 8q + jj; bpermute byte addr = 4*slot
                int s = __builtin_amdgcn_ds_bpermute(128 * h + vq + 4 * jj, idxs);
                float x = x_in[s * 16 + r];
                xv[jj] = ((8 * q + jj) < remS) ? x : 0.0f;
            }
            u32x4 t;
            #pragma unroll
            for (int d = 0; d < 4; ++d) t[d] = pkh(xv[2 * d], xv[2 * d + 1]);
            ax[h] = __builtin_bit_cast(f16x8, t);
        }

        // ---- h1 (lane = slot): pos already prefetched ----
        float d0 = pi0 - pox;
        float d1 = pi1 - poy;
        float d2 = pi2 - poz;
        unsigned int hp[8];
        #pragma unroll
        for (int cp = 0; cp < 8; ++cp) {
            float a0 = celu1(fmaf(d0, w1a[2 * cp],     fmaf(d1, w1b[2 * cp],     d2 * w1c[2 * cp])));
            float a1 = celu1(fmaf(d0, w1a[2 * cp + 1], fmaf(d1, w1b[2 * cp + 1], d2 * w1c[2 * cp + 1])));
            hp[cp] = pkh(a0, a1);
        }
        *(u32x4*)(H2L + lane * 48)      = (u32x4){hp[0], hp[1], hp[2], hp[3]};
        *(u32x4*)(H2L + lane * 48 + 16) = (u32x4){hp[4], hp[5], hp[6], hp[7]};
        f16x8 af[4];
        #pragma unroll
        for (int et = 0; et < 4; ++et) {
            int abase = (q < 2) ? ((et * 16 + r) * 48 + q * 16) : 9200;
            af[et] = __builtin_bit_cast(f16x8, *(const u32x4*)(H2L + abase));
        }

        // ---- h2 = celu(h1 @ W2) via MFMA; tile write H2L[m][slot] ----
        #pragma unroll
        for (int pp = 0; pp < 2; ++pp) {
            f32x4 D[4][2];
            #pragma unroll
            for (int et = 0; et < 4; ++et)
                #pragma unroll
                for (int j = 0; j < 2; ++j)
                    D[et][j] = __builtin_amdgcn_mfma_f32_16x16x32_f16(
                        af[et], bfr[2 * pp + j], (f32x4){0.f, 0.f, 0.f, 0.f}, 0, 0, 0);
            #pragma unroll
            for (int et = 0; et < 4; ++et)
                #pragma unroll
                for (int j = 0; j < 2; ++j) {
                    int nt = 2 * pp + j;
                    float v0 = celu1(D[et][j][0]);
                    float v1 = celu1(D[et][j][1]);
                    float v2 = celu1(D[et][j][2]);
                    float v3 = celu1(D[et][j][3]);
                    *(u32x2*)(H2L + (nt * 16 + r) * 144 + et * 32 + q * 8) =
                        (u32x2){pkh(v0, v1), pkh(v2, v3)};
                }
        }

        // ---- pos prefetch for next batch (idxs_next has landed by now) ----
        float pi0n = pos_in[idxs_next * 3 + 0];
        float pi1n = pos_in[idxs_next * 3 + 1];
        float pi2n = pos_in[idxs_next * 3 + 2];

        // ---- P accumulation per half, flush on wave-uniform transitions ----
        #pragma unroll
        for (int h = 0; h < 2; ++h) {
            int nS  = h ? nB : nA;
            int cfS = h ? cfB : cfA;
            if (rfl(nS) != cur_n) {
                float inv = cur_cf > 0 ? 1.0f / (float)cur_cf : 0.0f;
                #pragma unroll
                for (int mt = 0; mt < 4; ++mt)
                    #pragma unroll
                    for (int i = 0; i < 4; ++i)
                        Pf16[(size_t)cur_n * 1024 + (q * 4 + i) * 64 + mt * 16 + r] =
                            (__fp16)(C[mt][i] * inv);
                #pragma unroll
                for (int mt = 0; mt < 4; ++mt) C[mt] = (f32x4){0.f, 0.f, 0.f, 0.f};
                cur_n = nS; cur_cf = cfS;
            }
            #pragma unroll
            for (int mt = 0; mt < 4; ++mt) {
                f16x8 bb = __builtin_bit_cast(f16x8,
                    *(u32x4*)(H2L + (mt * 16 + r) * 144 + h * 64 + q * 16));
                C[mt] = __builtin_amdgcn_mfma_f32_16x16x32_f16(ax[h], bb, C[mt], 0, 0, 0);
            }
        }

        // ---- rotate pipeline registers ----
        nA = nA2; cfA = cfA2; remA = remA2; ebA = ebA2;
        nB = nB2; cfB = cfB2; remB = remB2; ebB = ebB2;
        idxs = idxs_next;
        pox = pox2; poy = poy2; poz = poz2;
        pi0 = pi0n; pi1 = pi1n; pi2 = pi2n;
    }

    // final flush
    {
        float inv = cur_cf > 0 ? 1.0f / (float)cur_cf : 0.0f;
        #pragma unroll
        for (int mt = 0; mt < 4; ++mt)
            #pragma unroll
            for (int i = 0; i < 4; ++i)
                Pf16[(size_t)cur_n * 1024 + (q * 4 + i) * 64 + mt * 16 + r] =
                    (__fp16)(C[mt][i] * inv);
    }
    #undef STEP_DESC
}

// ---------------- Kernel 2: out = Pf16 @ W3 + b3 (f16 MFMA, reg-blocked) -----
// Wave computes 2 ptiles (32 points) x all 64 out cols; B reused across ptiles.
__global__ __launch_bounds__(256) void gemm_kernel(
    const __fp16* __restrict__ Pf16,
    const __fp16* __restrict__ W3frag,
    const float* __restrict__ b3, float* __restrict__ out)
{
    int lane = threadIdx.x & 63;
    int w = blockIdx.x * 4 + (threadIdx.x >> 6);   // 1024 waves
    int quad = lane >> 4;
    int r = lane & 15;

    const short8* A0 = (const short8*)(Pf16 + (size_t)(w * 32 + r) * 1024 + quad * 8);
    const short8* A1 = A0 + 2048;                  // +16 rows (16*1024/8)
    const short8* Bp = (const short8*)W3frag + lane;

    f32x4 C[2][4];
    #pragma unroll
    for (int pt = 0; pt < 2; ++pt)
        #pragma unroll
        for (int nt = 0; nt < 4; ++nt) C[pt][nt] = (f32x4){0.f, 0.f, 0.f, 0.f};

    #pragma unroll 4
    for (int kk = 0; kk < 32; ++kk) {
        f16x8 a0 = __builtin_bit_cast(f16x8, A0[kk * 4]);
        f16x8 a1 = __builtin_bit_cast(f16x8, A1[kk * 4]);
        #pragma unroll
        for (int nt = 0; nt < 4; ++nt) {
            f16x8 bfrag = __builtin_bit_cast(f16x8, Bp[(size_t)(kk * 4 + nt) * 64]);
            C[0][nt] = __builtin_amdgcn_mfma_f32_16x16x32_f16(a0, bfrag, C[0][nt], 0, 0, 0);
            C[1][nt] = __builtin_amdgcn_mfma_f32_16x16x32_f16(a1, bfrag, C[1][nt], 0, 0, 0);
        }
    }

    #pragma unroll
    for (int pt = 0; pt < 2; ++pt)
        #pragma unroll
        for (int nt = 0; nt < 4; ++nt) {
            int outcol = nt * 16 + r;
            float bias = b3[outcol];
            #pragma unroll
            for (int i = 0; i < 4; ++i) {
                int prow = w * 32 + pt * 16 + quad * 4 + i;
                out[(size_t)prow * 64 + outcol] = C[pt][nt][i] + bias;
            }
        }
}

extern "C" void kernel_launch(void* const* d_in, const int* in_sizes, int n_in,
                              void* d_out, int out_size, void* d_ws, size_t ws_size,
                              hipStream_t stream)
{
    const float* x_in    = (const float*)d_in[0];
    const float* pos_in  = (const float*)d_in[1];
    const float* pos_out = (const float*)d_in[2];
    const int* in_index  = (const int*)d_in[3];
    const int* out_index = (const int*)d_in[4];
    const float* W1 = (const float*)d_in[5];
    const float* W2 = (const float*)d_in[6];
    const float* W3 = (const float*)d_in[7];
    const float* b3 = (const float*)d_in[8];

    int N = in_sizes[0] / 16;    // 32768
    int E = in_sizes[3];         // 786432
    float* out = (float*)d_out;

    // workspace: Pf16 (64MB) | seg (N+1) | W3frag (128KB) | W2f16 (4KB)
    char* ws = (char*)d_ws;
    __fp16* Pf16 = (__fp16*)ws;
    size_t off = (size_t)N * 1024 * 2;
    int* seg = (int*)(ws + off);
    off += (((size_t)(N + 1) * 4 + 255) & ~(size_t)255);
    __fp16* W3frag = (__fp16*)(ws + off);
    off += (size_t)65536 * 2;
    unsigned int* W2f16 = (unsigned int*)(ws + off);

    setup_kernel<<<(E + 255) / 256, 256, 0, stream>>>(out_index, seg, E, N,
                                                      W3, W2, W3frag, W2f16);
    agg_kernel<<<N / 8, 256, 0, stream>>>(x_in, pos_in, pos_out, in_index, seg,
                                          W1, W2f16, Pf16, E);
    gemm_kernel<<<N / 128, 256, 0, stream>>>(Pf16, W3frag, b3, out);
}